// Round 9
// baseline (1287.064 us; speedup 1.0000x reference)
//
#include <hip/hip_runtime.h>
#include <cmath>

#define B_ 4
#define C_ 256
#define P_ 4096   // H*W
#define N_ 4096   // tokens per batch (raw-reshape token count)

typedef __bf16 bf16x8 __attribute__((ext_vector_type(8)));
typedef __bf16 bf16x4 __attribute__((ext_vector_type(4)));
typedef float  f32x4  __attribute__((ext_vector_type(4)));

// ---------------------------------------------------------------------------
// Projection GEMM (fp32 compute) with bf16 hi/lo split output.
// Y viewed linearly IS the (n,c) token matrix (raw-reshape identity).
// ---------------------------------------------------------------------------
__global__ __launch_bounds__(256) void proj_kernel(
    const float* __restrict__ X, const float* __restrict__ W,
    const float* __restrict__ bias,
    __bf16* __restrict__ Yh, __bf16* __restrict__ Yl)
{
    const int p0 = blockIdx.x * 64;
    const int o0 = blockIdx.y * 64;
    const int b  = blockIdx.z;

    const float* Xb = X + (size_t)b * C_ * P_;
    const size_t ybase = (size_t)b * C_ * P_;

    __shared__ float WsT[32][68];
    __shared__ float Xs[32][64];

    const int tid = threadIdx.x;
    const int tx = tid & 15, ty = tid >> 4;

    float acc[4][4] = {};

    for (int kk = 0; kk < C_; kk += 32) {
        __syncthreads();
        #pragma unroll
        for (int i = 0; i < 8; ++i) {
            int flat = tid + i * 256;
            int r = flat >> 5, c = flat & 31;
            WsT[c][r] = W[(o0 + r) * C_ + (kk + c)];
        }
        #pragma unroll
        for (int i = 0; i < 8; ++i) {
            int flat = tid + i * 256;
            int r = flat >> 6, c = flat & 63;
            Xs[r][c] = Xb[(size_t)(kk + r) * P_ + (p0 + c)];
        }
        __syncthreads();
        #pragma unroll
        for (int k = 0; k < 32; ++k) {
            float4 a4 = *(const float4*)&WsT[k][ty * 4];
            float4 x4 = *(const float4*)&Xs[k][tx * 4];
            const float av[4] = {a4.x, a4.y, a4.z, a4.w};
            const float xv[4] = {x4.x, x4.y, x4.z, x4.w};
            #pragma unroll
            for (int i = 0; i < 4; ++i)
                #pragma unroll
                for (int j = 0; j < 4; ++j)
                    acc[i][j] += av[i] * xv[j];
        }
    }

    #pragma unroll
    for (int i = 0; i < 4; ++i) {
        float bv = bias[o0 + ty * 4 + i];
        bf16x4 h, l;
        #pragma unroll
        for (int j = 0; j < 4; ++j) {
            float y  = acc[i][j] + bv;
            __bf16 hh = (__bf16)y;
            __bf16 ll = (__bf16)(y - (float)hh);
            h[j] = hh; l[j] = ll;
        }
        size_t off = ybase + (size_t)(o0 + ty * 4 + i) * P_ + p0 + tx * 4;
        *(bf16x4*)&Yh[off] = h;
        *(bf16x4*)&Yl[off] = l;
    }
}

// ---------------------------------------------------------------------------
// Transpose V (n,c) -> Vt (c,n), bf16 bits. grid (64, 4, 8): z = b*2 + buf.
// ---------------------------------------------------------------------------
__global__ __launch_bounds__(256) void transpose_kernel(
    const ushort* __restrict__ SrcH, const ushort* __restrict__ SrcL,
    ushort* __restrict__ DstH, ushort* __restrict__ DstL)
{
    const int n0 = blockIdx.x * 64;
    const int c0 = blockIdx.y * 64;
    const int b  = blockIdx.z >> 1;
    const int bf = blockIdx.z & 1;

    const ushort* src = (bf ? SrcL : SrcH) + (size_t)b * N_ * C_;
    ushort*       dst = (bf ? DstL : DstH) + (size_t)b * N_ * C_;

    __shared__ ushort T[64][65];
    const int tid = threadIdx.x;

    #pragma unroll
    for (int it = 0; it < 4; ++it) {
        int e = tid + it * 256;
        int r = e >> 4, c4 = (e & 15) * 4;
        *(ushort4*)&T[r][c4] = *(const ushort4*)&src[(size_t)(n0 + r) * C_ + c0 + c4];
    }
    __syncthreads();
    #pragma unroll
    for (int it = 0; it < 4; ++it) {
        int e = tid + it * 256;
        int cr = e >> 4, nl = (e & 15) * 4;
        ushort4 v;
        v.x = T[nl + 0][cr]; v.y = T[nl + 1][cr];
        v.z = T[nl + 2][cr]; v.w = T[nl + 3][cr];
        *(ushort4*)&dst[(size_t)(c0 + cr) * N_ + n0 + nl] = v;
    }
}

// ---------------------------------------------------------------------------
// Split-bf16 MFMA flash attention, IN-BLOCK m-split (flash-decoding w/o ws).
// grid (N/16, B), block 256 = 4 waves. All 4 waves share the SAME 16 q-rows
// (n0..n0+15); wave w covers m in [w*1024, (w+1)*1024) (16 tiles of 64).
// End-of-block: waves 1-3 dump unnormalized O + (m,l) to LDS; wave 0 merges
// with exp rescaling and writes the final normalized rows.
// LDS: max(Pl 18KB, CMB 49.9KB) + ML 0.4KB ~= 50.3KB -> 3 blocks/CU
//      = 12 waves/CU = 3 waves/SIMD (VGPR 140*3=420<=512).
// ---------------------------------------------------------------------------
#define MLEN (N_ / 4)   // 1024 tokens per wave

__global__ __launch_bounds__(256) void attn_kernel(
    const __bf16* __restrict__ Qh, const __bf16* __restrict__ Ql,
    const __bf16* __restrict__ Kh, const __bf16* __restrict__ Kl,
    const __bf16* __restrict__ Vth, const __bf16* __restrict__ Vtl,
    float* __restrict__ O)
{
    const int b  = blockIdx.y;
    const int n0 = blockIdx.x * 16;
    const size_t base = (size_t)b * N_ * C_;

    const int tid  = threadIdx.x;
    const int w    = tid >> 6;
    const int lane = tid & 63;
    const int l15  = lane & 15;
    const int lg   = lane >> 4;

    // ---- shared memory overlay: Pl (loop phase) / CMB+MLs (combine phase) --
    __shared__ __align__(16) char smem[3 * 16 * 260 * 4 + 3 * 16 * 2 * 4];
    __bf16 (*Pl)[2][16][72] = (__bf16 (*)[2][16][72])smem;   // [4][2][16][72]
    float (*CMB)[16][260]   = (float (*)[16][260])smem;      // [3][16][260]
    float* MLs = (float*)(smem + 3 * 16 * 260 * 4);          // [3][16][2]

    // ---- Q fragments (same rows for all waves): row = l15, k = kk*32+lg*8 --
    const __bf16* qh_p = Qh + base + (size_t)(n0 + l15) * C_ + lg * 8;
    const __bf16* ql_p = Ql + base + (size_t)(n0 + l15) * C_ + lg * 8;
    bf16x8 qfh[8], qfl[8];
    #pragma unroll
    for (int k = 0; k < 8; ++k) {
        qfh[k] = *(const bf16x8*)(qh_p + k * 32);
        qfl[k] = *(const bf16x8*)(ql_p + k * 32);
    }

    f32x4 oc[16];
    #pragma unroll
    for (int c = 0; c < 16; ++c) oc[c] = (f32x4){0.f, 0.f, 0.f, 0.f};
    float m_run[4] = {-1e30f, -1e30f, -1e30f, -1e30f};
    float l_run[4] = {0.f, 0.f, 0.f, 0.f};

    const int m_lo = w * MLEN;
    for (int mt0 = 0; mt0 < MLEN; mt0 += 64) {
        const int mt = m_lo + mt0;
        // ---------------- S = Q K^T ----------------
        f32x4 sacc[4];
        #pragma unroll
        for (int js = 0; js < 4; ++js) sacc[js] = (f32x4){0.f, 0.f, 0.f, 0.f};

        const __bf16* kh_p = Kh + base + (size_t)(mt + l15) * C_ + lg * 8;
        const __bf16* kl_p = Kl + base + (size_t)(mt + l15) * C_ + lg * 8;

        #pragma unroll
        for (int kk = 0; kk < 8; ++kk) {
            #pragma unroll
            for (int js = 0; js < 4; ++js) {
                bf16x8 kfh = *(const bf16x8*)(kh_p + js * 16 * C_ + kk * 32);
                bf16x8 kfl = *(const bf16x8*)(kl_p + js * 16 * C_ + kk * 32);
                sacc[js] = __builtin_amdgcn_mfma_f32_16x16x32_bf16(qfh[kk], kfh, sacc[js], 0, 0, 0);
                sacc[js] = __builtin_amdgcn_mfma_f32_16x16x32_bf16(qfh[kk], kfl, sacc[js], 0, 0, 0);
                sacc[js] = __builtin_amdgcn_mfma_f32_16x16x32_bf16(qfl[kk], kfh, sacc[js], 0, 0, 0);
            }
        }

        // ---------------- online softmax (rows lg*4+r) ----------------
        float scale_[4];
        #pragma unroll
        for (int r = 0; r < 4; ++r) {
            float mx = fmaxf(fmaxf(sacc[0][r], sacc[1][r]), fmaxf(sacc[2][r], sacc[3][r]));
            #pragma unroll
            for (int d = 1; d < 16; d <<= 1)
                mx = fmaxf(mx, __shfl_xor(mx, d, 64));
            float mnew = fmaxf(m_run[r], mx);
            scale_[r] = __expf(m_run[r] - mnew);
            float ss = 0.f;
            #pragma unroll
            for (int js = 0; js < 4; ++js) {
                float pv = __expf(sacc[js][r] - mnew);
                sacc[js][r] = pv;
                ss += pv;
            }
            #pragma unroll
            for (int d = 1; d < 16; d <<= 1)
                ss += __shfl_xor(ss, d, 64);
            l_run[r] = l_run[r] * scale_[r] + ss;
            m_run[r] = mnew;
        }

        // ---- P -> LDS (hi/lo), wave-private region; no block barrier ----
        #pragma unroll
        for (int js = 0; js < 4; ++js)
            #pragma unroll
            for (int r = 0; r < 4; ++r) {
                float pv = sacc[js][r];
                __bf16 hh = (__bf16)pv;
                __bf16 ll = (__bf16)(pv - (float)hh);
                Pl[w][0][lg * 4 + r][js * 16 + l15] = hh;
                Pl[w][1][lg * 4 + r][js * 16 + l15] = ll;
            }

        #pragma unroll
        for (int c = 0; c < 16; ++c)
            #pragma unroll
            for (int r = 0; r < 4; ++r)
                oc[c][r] *= scale_[r];

        // within-wave RAW on Pl: compiler emits lgkmcnt wait (same object)
        bf16x8 pah0 = *(const bf16x8*)&Pl[w][0][l15][lg * 8];
        bf16x8 pah1 = *(const bf16x8*)&Pl[w][0][l15][32 + lg * 8];
        bf16x8 pal0 = *(const bf16x8*)&Pl[w][1][l15][lg * 8];
        bf16x8 pal1 = *(const bf16x8*)&Pl[w][1][l15][32 + lg * 8];

        // ---------------- O += P V ----------------
        const __bf16* vh_p = Vth + base + (size_t)l15 * N_ + mt + lg * 8;
        const __bf16* vl_p = Vtl + base + (size_t)l15 * N_ + mt + lg * 8;
        #pragma unroll
        for (int cs = 0; cs < 16; ++cs) {
            const __bf16* vh_c = vh_p + (size_t)cs * 16 * N_;
            const __bf16* vl_c = vl_p + (size_t)cs * 16 * N_;
            bf16x8 vh0 = *(const bf16x8*)(vh_c);
            bf16x8 vh1 = *(const bf16x8*)(vh_c + 32);
            bf16x8 vl0 = *(const bf16x8*)(vl_c);
            bf16x8 vl1 = *(const bf16x8*)(vl_c + 32);
            f32x4 a = oc[cs];
            a = __builtin_amdgcn_mfma_f32_16x16x32_bf16(pah0, vh0, a, 0, 0, 0);
            a = __builtin_amdgcn_mfma_f32_16x16x32_bf16(pah0, vl0, a, 0, 0, 0);
            a = __builtin_amdgcn_mfma_f32_16x16x32_bf16(pal0, vh0, a, 0, 0, 0);
            a = __builtin_amdgcn_mfma_f32_16x16x32_bf16(pah1, vh1, a, 0, 0, 0);
            a = __builtin_amdgcn_mfma_f32_16x16x32_bf16(pah1, vl1, a, 0, 0, 0);
            a = __builtin_amdgcn_mfma_f32_16x16x32_bf16(pal1, vh1, a, 0, 0, 0);
            oc[cs] = a;
        }
    }

    // ---------------- in-block combine of the 4 m-partials ----------------
    __syncthreads();   // Pl phase done everywhere; smem repurposed as CMB/MLs

    if (w > 0) {
        #pragma unroll
        for (int cs = 0; cs < 16; ++cs)
            #pragma unroll
            for (int r = 0; r < 4; ++r)
                CMB[w - 1][lg * 4 + r][cs * 16 + l15] = oc[cs][r];
        if (l15 == 0) {
            #pragma unroll
            for (int r = 0; r < 4; ++r) {
                MLs[((w - 1) * 16 + lg * 4 + r) * 2 + 0] = m_run[r];
                MLs[((w - 1) * 16 + lg * 4 + r) * 2 + 1] = l_run[r];
            }
        }
    }

    __syncthreads();

    if (w == 0) {
        float myw[4], wws[3][4], inv[4];
        #pragma unroll
        for (int r = 0; r < 4; ++r) {
            const int row = lg * 4 + r;
            float M = m_run[r];
            #pragma unroll
            for (int wi = 0; wi < 3; ++wi)
                M = fmaxf(M, MLs[(wi * 16 + row) * 2 + 0]);
            myw[r] = __expf(m_run[r] - M);
            float lt = l_run[r] * myw[r];
            #pragma unroll
            for (int wi = 0; wi < 3; ++wi) {
                float ww = __expf(MLs[(wi * 16 + row) * 2 + 0] - M);
                wws[wi][r] = ww;
                lt += MLs[(wi * 16 + row) * 2 + 1] * ww;
            }
            inv[r] = 1.0f / lt;
        }
        #pragma unroll
        for (int cs = 0; cs < 16; ++cs)
            #pragma unroll
            for (int r = 0; r < 4; ++r) {
                const int row = lg * 4 + r;
                float v = oc[cs][r] * myw[r];
                #pragma unroll
                for (int wi = 0; wi < 3; ++wi)
                    v += CMB[wi][row][cs * 16 + l15] * wws[wi][r];
                O[base + (size_t)(n0 + row) * C_ + cs * 16 + l15] = v * inv[r];
            }
    }
}

// ---------------------------------------------------------------------------
extern "C" void kernel_launch(void* const* d_in, const int* in_sizes, int n_in,
                              void* d_out, int out_size, void* d_ws, size_t ws_size,
                              hipStream_t stream)
{
    const float* tgt = (const float*)d_in[0];
    const float* src = (const float*)d_in[1];
    const float* qw  = (const float*)d_in[2];
    const float* qb  = (const float*)d_in[3];
    const float* kw  = (const float*)d_in[4];
    const float* kb  = (const float*)d_in[5];
    const float* vw  = (const float*)d_in[6];
    const float* vb  = (const float*)d_in[7];
    float* out = (float*)d_out;

    // ws: 6 bf16 buffers (Qh Ql Kh Kl Vth Vtl) = 50.3 MB (proven fit)
    const size_t SZ = (size_t)B_ * N_ * C_;
    __bf16* w0 = (__bf16*)d_ws;
    __bf16* w1 = w0 + SZ;
    __bf16* w2 = w1 + SZ;
    __bf16* w3 = w2 + SZ;
    __bf16* w4 = w3 + SZ;
    __bf16* w5 = w4 + SZ;

    dim3 pgrid(P_ / 64, C_ / 64, B_);
    // 1) V projection -> Vnc (into future-Q region)
    proj_kernel<<<pgrid, 256, 0, stream>>>(src, vw, vb, w0, w1);
    // 2) transpose Vnc -> Vt
    dim3 tgrid(N_ / 64, C_ / 64, B_ * 2);
    transpose_kernel<<<tgrid, 256, 0, stream>>>(
        (const ushort*)w0, (const ushort*)w1, (ushort*)w4, (ushort*)w5);
    // 3) Q projection (overwrites dead Vnc)
    proj_kernel<<<pgrid, 256, 0, stream>>>(tgt, qw, qb, w0, w1);
    // 4) K projection
    proj_kernel<<<pgrid, 256, 0, stream>>>(src, kw, kb, w2, w3);
    // 5) attention, in-block m-split (no extra workspace)
    dim3 agrid(N_ / 16, B_);
    attn_kernel<<<agrid, 256, 0, stream>>>(w0, w1, w2, w3, w4, w5, out);
}

// Round 10
// 978.099 us; speedup vs baseline: 1.3159x; 1.3159x over previous
//
#include <hip/hip_runtime.h>
#include <cmath>

#define B_ 4
#define C_ 256
#define P_ 4096   // H*W
#define N_ 4096   // tokens per batch (raw-reshape token count)

typedef __bf16 bf16x8 __attribute__((ext_vector_type(8)));
typedef __bf16 bf16x4 __attribute__((ext_vector_type(4)));
typedef float  f32x4  __attribute__((ext_vector_type(4)));

// ---------------------------------------------------------------------------
// Projection GEMM (fp32 compute) with bf16 hi/lo split output.
// Y viewed linearly IS the (n,c) token matrix (raw-reshape identity).
// ---------------------------------------------------------------------------
__global__ __launch_bounds__(256) void proj_kernel(
    const float* __restrict__ X, const float* __restrict__ W,
    const float* __restrict__ bias,
    __bf16* __restrict__ Yh, __bf16* __restrict__ Yl)
{
    const int p0 = blockIdx.x * 64;
    const int o0 = blockIdx.y * 64;
    const int b  = blockIdx.z;

    const float* Xb = X + (size_t)b * C_ * P_;
    const size_t ybase = (size_t)b * C_ * P_;

    __shared__ float WsT[32][68];
    __shared__ float Xs[32][64];

    const int tid = threadIdx.x;
    const int tx = tid & 15, ty = tid >> 4;

    float acc[4][4] = {};

    for (int kk = 0; kk < C_; kk += 32) {
        __syncthreads();
        #pragma unroll
        for (int i = 0; i < 8; ++i) {
            int flat = tid + i * 256;
            int r = flat >> 5, c = flat & 31;
            WsT[c][r] = W[(o0 + r) * C_ + (kk + c)];
        }
        #pragma unroll
        for (int i = 0; i < 8; ++i) {
            int flat = tid + i * 256;
            int r = flat >> 6, c = flat & 63;
            Xs[r][c] = Xb[(size_t)(kk + r) * P_ + (p0 + c)];
        }
        __syncthreads();
        #pragma unroll
        for (int k = 0; k < 32; ++k) {
            float4 a4 = *(const float4*)&WsT[k][ty * 4];
            float4 x4 = *(const float4*)&Xs[k][tx * 4];
            const float av[4] = {a4.x, a4.y, a4.z, a4.w};
            const float xv[4] = {x4.x, x4.y, x4.z, x4.w};
            #pragma unroll
            for (int i = 0; i < 4; ++i)
                #pragma unroll
                for (int j = 0; j < 4; ++j)
                    acc[i][j] += av[i] * xv[j];
        }
    }

    #pragma unroll
    for (int i = 0; i < 4; ++i) {
        float bv = bias[o0 + ty * 4 + i];
        bf16x4 h, l;
        #pragma unroll
        for (int j = 0; j < 4; ++j) {
            float y  = acc[i][j] + bv;
            __bf16 hh = (__bf16)y;
            __bf16 ll = (__bf16)(y - (float)hh);
            h[j] = hh; l[j] = ll;
        }
        size_t off = ybase + (size_t)(o0 + ty * 4 + i) * P_ + p0 + tx * 4;
        *(bf16x4*)&Yh[off] = h;
        *(bf16x4*)&Yl[off] = l;
    }
}

// ---------------------------------------------------------------------------
// Transpose V (n,c) -> Vt (c,n), bf16 bits. grid (64, 4, 8): z = b*2 + buf.
// ---------------------------------------------------------------------------
__global__ __launch_bounds__(256) void transpose_kernel(
    const ushort* __restrict__ SrcH, const ushort* __restrict__ SrcL,
    ushort* __restrict__ DstH, ushort* __restrict__ DstL)
{
    const int n0 = blockIdx.x * 64;
    const int c0 = blockIdx.y * 64;
    const int b  = blockIdx.z >> 1;
    const int bf = blockIdx.z & 1;

    const ushort* src = (bf ? SrcL : SrcH) + (size_t)b * N_ * C_;
    ushort*       dst = (bf ? DstL : DstH) + (size_t)b * N_ * C_;

    __shared__ ushort T[64][65];
    const int tid = threadIdx.x;

    #pragma unroll
    for (int it = 0; it < 4; ++it) {
        int e = tid + it * 256;
        int r = e >> 4, c4 = (e & 15) * 4;
        *(ushort4*)&T[r][c4] = *(const ushort4*)&src[(size_t)(n0 + r) * C_ + c0 + c4];
    }
    __syncthreads();
    #pragma unroll
    for (int it = 0; it < 4; ++it) {
        int e = tid + it * 256;
        int cr = e >> 4, nl = (e & 15) * 4;
        ushort4 v;
        v.x = T[nl + 0][cr]; v.y = T[nl + 1][cr];
        v.z = T[nl + 2][cr]; v.w = T[nl + 3][cr];
        *(ushort4*)&dst[(size_t)(c0 + cr) * N_ + n0 + nl] = v;
    }
}

// ---------------------------------------------------------------------------
// Split-bf16 MFMA flash attention with cooperative LDS staging of K/V tiles.
// grid (N/64, B), block 256 = 4 waves. Wave w owns q-rows n0+w*16..+15; all
// 4 waves sweep the same m-tiles, sharing ONE staged copy of K/V per tile
// (4x fewer global transactions vs per-wave direct loads; coalesced).
// LDS: K 2x33KB + Vt 2x36KB + P 18KB = 156KB -> 1 block/CU (by design:
// measured round 6 vs 9 shows dur is occupancy-invariant; the limiter is
// per-CU transaction throughput, which staging attacks directly).
// Padding +8 elems -> row strides 264/72 elems: 2-way bank aliasing = free.
// ---------------------------------------------------------------------------
__global__ __launch_bounds__(256) void attn_kernel(
    const __bf16* __restrict__ Qh, const __bf16* __restrict__ Ql,
    const __bf16* __restrict__ Kh, const __bf16* __restrict__ Kl,
    const __bf16* __restrict__ Vth, const __bf16* __restrict__ Vtl,
    float* __restrict__ O)
{
    const int b  = blockIdx.y;
    const int n0 = blockIdx.x * 64;
    const size_t base = (size_t)b * N_ * C_;

    const int tid  = threadIdx.x;
    const int w    = tid >> 6;
    const int lane = tid & 63;
    const int l15  = lane & 15;
    const int lg   = lane >> 4;

    __shared__ __align__(16) __bf16 KshH[64][264];   // 33792 B
    __shared__ __align__(16) __bf16 KshL[64][264];
    __shared__ __align__(16) __bf16 VshH[256][72];   // 36864 B
    __shared__ __align__(16) __bf16 VshL[256][72];
    __shared__ __align__(16) __bf16 Pl[4][2][16][72];// 18432 B  => 156 KiB

    // ---- Q fragments: row = l15 (q-row n0+w*16+l15), k = kk*32+lg*8 ----
    const __bf16* qh_p = Qh + base + (size_t)(n0 + w * 16 + l15) * C_ + lg * 8;
    const __bf16* ql_p = Ql + base + (size_t)(n0 + w * 16 + l15) * C_ + lg * 8;
    bf16x8 qfh[8], qfl[8];
    #pragma unroll
    for (int k = 0; k < 8; ++k) {
        qfh[k] = *(const bf16x8*)(qh_p + k * 32);
        qfl[k] = *(const bf16x8*)(ql_p + k * 32);
    }

    f32x4 oc[16];
    #pragma unroll
    for (int c = 0; c < 16; ++c) oc[c] = (f32x4){0.f, 0.f, 0.f, 0.f};
    float m_run[4] = {-1e30f, -1e30f, -1e30f, -1e30f};
    float l_run[4] = {0.f, 0.f, 0.f, 0.f};

    for (int mt = 0; mt < N_; mt += 64) {
        // ---------------- cooperative staging (coalesced) ----------------
        __syncthreads();   // previous tile's LDS reads complete
        {
            // K tile: 64 rows x 256 c; 2048 chunks of 16B per buffer
            #pragma unroll
            for (int i = 0; i < 8; ++i) {
                int f = i * 256 + tid;
                int r = f >> 5, c8 = (f & 31) * 8;
                *(bf16x8*)&KshH[r][c8] =
                    *(const bf16x8*)(Kh + base + (size_t)(mt + r) * C_ + c8);
            }
            #pragma unroll
            for (int i = 0; i < 8; ++i) {
                int f = i * 256 + tid;
                int r = f >> 5, c8 = (f & 31) * 8;
                *(bf16x8*)&KshL[r][c8] =
                    *(const bf16x8*)(Kl + base + (size_t)(mt + r) * C_ + c8);
            }
            // Vt tile: 256 rows (c) x 64 m; 2048 chunks of 8 elems per buffer
            #pragma unroll
            for (int i = 0; i < 8; ++i) {
                int f = i * 256 + tid;
                int c = f >> 3, m8 = (f & 7) * 8;
                *(bf16x8*)&VshH[c][m8] =
                    *(const bf16x8*)(Vth + base + (size_t)c * N_ + mt + m8);
            }
            #pragma unroll
            for (int i = 0; i < 8; ++i) {
                int f = i * 256 + tid;
                int c = f >> 3, m8 = (f & 7) * 8;
                *(bf16x8*)&VshL[c][m8] =
                    *(const bf16x8*)(Vtl + base + (size_t)c * N_ + mt + m8);
            }
        }
        __syncthreads();   // staged data visible to all waves

        // ---------------- S = Q K^T (B-frags from LDS) ----------------
        f32x4 sacc[4];
        #pragma unroll
        for (int js = 0; js < 4; ++js) sacc[js] = (f32x4){0.f, 0.f, 0.f, 0.f};

        #pragma unroll
        for (int kk = 0; kk < 8; ++kk) {
            #pragma unroll
            for (int js = 0; js < 4; ++js) {
                bf16x8 kfh = *(const bf16x8*)&KshH[js * 16 + l15][kk * 32 + lg * 8];
                bf16x8 kfl = *(const bf16x8*)&KshL[js * 16 + l15][kk * 32 + lg * 8];
                sacc[js] = __builtin_amdgcn_mfma_f32_16x16x32_bf16(qfh[kk], kfh, sacc[js], 0, 0, 0);
                sacc[js] = __builtin_amdgcn_mfma_f32_16x16x32_bf16(qfh[kk], kfl, sacc[js], 0, 0, 0);
                sacc[js] = __builtin_amdgcn_mfma_f32_16x16x32_bf16(qfl[kk], kfh, sacc[js], 0, 0, 0);
            }
        }

        // ---------------- online softmax (rows lg*4+r) ----------------
        float scale_[4];
        #pragma unroll
        for (int r = 0; r < 4; ++r) {
            float mx = fmaxf(fmaxf(sacc[0][r], sacc[1][r]), fmaxf(sacc[2][r], sacc[3][r]));
            #pragma unroll
            for (int d = 1; d < 16; d <<= 1)
                mx = fmaxf(mx, __shfl_xor(mx, d, 64));
            float mnew = fmaxf(m_run[r], mx);
            scale_[r] = __expf(m_run[r] - mnew);
            float ss = 0.f;
            #pragma unroll
            for (int js = 0; js < 4; ++js) {
                float pv = __expf(sacc[js][r] - mnew);
                sacc[js][r] = pv;
                ss += pv;
            }
            #pragma unroll
            for (int d = 1; d < 16; d <<= 1)
                ss += __shfl_xor(ss, d, 64);
            l_run[r] = l_run[r] * scale_[r] + ss;
            m_run[r] = mnew;
        }

        // ---- P -> wave-private LDS (hi/lo); within-wave RAW, no barrier ----
        #pragma unroll
        for (int js = 0; js < 4; ++js)
            #pragma unroll
            for (int r = 0; r < 4; ++r) {
                float pv = sacc[js][r];
                __bf16 hh = (__bf16)pv;
                __bf16 ll = (__bf16)(pv - (float)hh);
                Pl[w][0][lg * 4 + r][js * 16 + l15] = hh;
                Pl[w][1][lg * 4 + r][js * 16 + l15] = ll;
            }

        #pragma unroll
        for (int c = 0; c < 16; ++c)
            #pragma unroll
            for (int r = 0; r < 4; ++r)
                oc[c][r] *= scale_[r];

        bf16x8 pah0 = *(const bf16x8*)&Pl[w][0][l15][lg * 8];
        bf16x8 pah1 = *(const bf16x8*)&Pl[w][0][l15][32 + lg * 8];
        bf16x8 pal0 = *(const bf16x8*)&Pl[w][1][l15][lg * 8];
        bf16x8 pal1 = *(const bf16x8*)&Pl[w][1][l15][32 + lg * 8];

        // ---------------- O += P V (B-frags from LDS) ----------------
        #pragma unroll
        for (int cs = 0; cs < 16; ++cs) {
            bf16x8 vh0 = *(const bf16x8*)&VshH[cs * 16 + l15][lg * 8];
            bf16x8 vh1 = *(const bf16x8*)&VshH[cs * 16 + l15][32 + lg * 8];
            bf16x8 vl0 = *(const bf16x8*)&VshL[cs * 16 + l15][lg * 8];
            bf16x8 vl1 = *(const bf16x8*)&VshL[cs * 16 + l15][32 + lg * 8];
            f32x4 a = oc[cs];
            a = __builtin_amdgcn_mfma_f32_16x16x32_bf16(pah0, vh0, a, 0, 0, 0);
            a = __builtin_amdgcn_mfma_f32_16x16x32_bf16(pah0, vl0, a, 0, 0, 0);
            a = __builtin_amdgcn_mfma_f32_16x16x32_bf16(pal0, vh0, a, 0, 0, 0);
            a = __builtin_amdgcn_mfma_f32_16x16x32_bf16(pah1, vh1, a, 0, 0, 0);
            a = __builtin_amdgcn_mfma_f32_16x16x32_bf16(pah1, vl1, a, 0, 0, 0);
            a = __builtin_amdgcn_mfma_f32_16x16x32_bf16(pal1, vh1, a, 0, 0, 0);
            oc[cs] = a;
        }
    }

    // ---------------- epilogue: normalize + store ----------------
    float inv[4];
    #pragma unroll
    for (int r = 0; r < 4; ++r) inv[r] = 1.0f / l_run[r];
    #pragma unroll
    for (int cs = 0; cs < 16; ++cs)
        #pragma unroll
        for (int r = 0; r < 4; ++r)
            O[base + (size_t)(n0 + w * 16 + lg * 4 + r) * C_ + cs * 16 + l15] =
                oc[cs][r] * inv[r];
}

// ---------------------------------------------------------------------------
extern "C" void kernel_launch(void* const* d_in, const int* in_sizes, int n_in,
                              void* d_out, int out_size, void* d_ws, size_t ws_size,
                              hipStream_t stream)
{
    const float* tgt = (const float*)d_in[0];
    const float* src = (const float*)d_in[1];
    const float* qw  = (const float*)d_in[2];
    const float* qb  = (const float*)d_in[3];
    const float* kw  = (const float*)d_in[4];
    const float* kb  = (const float*)d_in[5];
    const float* vw  = (const float*)d_in[6];
    const float* vb  = (const float*)d_in[7];
    float* out = (float*)d_out;

    // ws: 6 bf16 buffers (Qh Ql Kh Kl Vth Vtl) = 50.3 MB (proven fit)
    const size_t SZ = (size_t)B_ * N_ * C_;
    __bf16* w0 = (__bf16*)d_ws;
    __bf16* w1 = w0 + SZ;
    __bf16* w2 = w1 + SZ;
    __bf16* w3 = w2 + SZ;
    __bf16* w4 = w3 + SZ;
    __bf16* w5 = w4 + SZ;

    dim3 pgrid(P_ / 64, C_ / 64, B_);
    // 1) V projection -> Vnc (into future-Q region)
    proj_kernel<<<pgrid, 256, 0, stream>>>(src, vw, vb, w0, w1);
    // 2) transpose Vnc -> Vt
    dim3 tgrid(N_ / 64, C_ / 64, B_ * 2);
    transpose_kernel<<<tgrid, 256, 0, stream>>>(
        (const ushort*)w0, (const ushort*)w1, (ushort*)w4, (ushort*)w5);
    // 3) Q projection (overwrites dead Vnc)
    proj_kernel<<<pgrid, 256, 0, stream>>>(tgt, qw, qb, w0, w1);
    // 4) K projection
    proj_kernel<<<pgrid, 256, 0, stream>>>(src, kw, kb, w2, w3);
    // 5) attention with cooperative LDS staging
    dim3 agrid(N_ / 64, B_);
    attn_kernel<<<agrid, 256, 0, stream>>>(w0, w1, w2, w3, w4, w5, out);
}

// Round 11
// 549.157 us; speedup vs baseline: 2.3437x; 1.7811x over previous
//
#include <hip/hip_runtime.h>
#include <cmath>

#define B_ 4
#define C_ 256
#define P_ 4096   // H*W
#define N_ 4096   // tokens per batch (raw-reshape token count)

typedef __bf16 bf16x8 __attribute__((ext_vector_type(8)));
typedef __bf16 bf16x4 __attribute__((ext_vector_type(4)));
typedef float  f32x4  __attribute__((ext_vector_type(4)));

// ---------------------------------------------------------------------------
// Projection GEMM (fp32 compute) with bf16 hi/lo split output.
// Y viewed linearly IS the (n,c) token matrix (raw-reshape identity).
// ---------------------------------------------------------------------------
__global__ __launch_bounds__(256) void proj_kernel(
    const float* __restrict__ X, const float* __restrict__ W,
    const float* __restrict__ bias,
    __bf16* __restrict__ Yh, __bf16* __restrict__ Yl)
{
    const int p0 = blockIdx.x * 64;
    const int o0 = blockIdx.y * 64;
    const int b  = blockIdx.z;

    const float* Xb = X + (size_t)b * C_ * P_;
    const size_t ybase = (size_t)b * C_ * P_;

    __shared__ float WsT[32][68];
    __shared__ float Xs[32][64];

    const int tid = threadIdx.x;
    const int tx = tid & 15, ty = tid >> 4;

    float acc[4][4] = {};

    for (int kk = 0; kk < C_; kk += 32) {
        __syncthreads();
        #pragma unroll
        for (int i = 0; i < 8; ++i) {
            int flat = tid + i * 256;
            int r = flat >> 5, c = flat & 31;
            WsT[c][r] = W[(o0 + r) * C_ + (kk + c)];
        }
        #pragma unroll
        for (int i = 0; i < 8; ++i) {
            int flat = tid + i * 256;
            int r = flat >> 6, c = flat & 63;
            Xs[r][c] = Xb[(size_t)(kk + r) * P_ + (p0 + c)];
        }
        __syncthreads();
        #pragma unroll
        for (int k = 0; k < 32; ++k) {
            float4 a4 = *(const float4*)&WsT[k][ty * 4];
            float4 x4 = *(const float4*)&Xs[k][tx * 4];
            const float av[4] = {a4.x, a4.y, a4.z, a4.w};
            const float xv[4] = {x4.x, x4.y, x4.z, x4.w};
            #pragma unroll
            for (int i = 0; i < 4; ++i)
                #pragma unroll
                for (int j = 0; j < 4; ++j)
                    acc[i][j] += av[i] * xv[j];
        }
    }

    #pragma unroll
    for (int i = 0; i < 4; ++i) {
        float bv = bias[o0 + ty * 4 + i];
        bf16x4 h, l;
        #pragma unroll
        for (int j = 0; j < 4; ++j) {
            float y  = acc[i][j] + bv;
            __bf16 hh = (__bf16)y;
            __bf16 ll = (__bf16)(y - (float)hh);
            h[j] = hh; l[j] = ll;
        }
        size_t off = ybase + (size_t)(o0 + ty * 4 + i) * P_ + p0 + tx * 4;
        *(bf16x4*)&Yh[off] = h;
        *(bf16x4*)&Yl[off] = l;
    }
}

// ---------------------------------------------------------------------------
// Transpose V (n,c) -> Vt (c,n), bf16 bits. grid (64, 4, 8): z = b*2 + buf.
// ---------------------------------------------------------------------------
__global__ __launch_bounds__(256) void transpose_kernel(
    const ushort* __restrict__ SrcH, const ushort* __restrict__ SrcL,
    ushort* __restrict__ DstH, ushort* __restrict__ DstL)
{
    const int n0 = blockIdx.x * 64;
    const int c0 = blockIdx.y * 64;
    const int b  = blockIdx.z >> 1;
    const int bf = blockIdx.z & 1;

    const ushort* src = (bf ? SrcL : SrcH) + (size_t)b * N_ * C_;
    ushort*       dst = (bf ? DstL : DstH) + (size_t)b * N_ * C_;

    __shared__ ushort T[64][65];
    const int tid = threadIdx.x;

    #pragma unroll
    for (int it = 0; it < 4; ++it) {
        int e = tid + it * 256;
        int r = e >> 4, c4 = (e & 15) * 4;
        *(ushort4*)&T[r][c4] = *(const ushort4*)&src[(size_t)(n0 + r) * C_ + c0 + c4];
    }
    __syncthreads();
    #pragma unroll
    for (int it = 0; it < 4; ++it) {
        int e = tid + it * 256;
        int cr = e >> 4, nl = (e & 15) * 4;
        ushort4 v;
        v.x = T[nl + 0][cr]; v.y = T[nl + 1][cr];
        v.z = T[nl + 2][cr]; v.w = T[nl + 3][cr];
        *(ushort4*)&dst[(size_t)(c0 + cr) * N_ + n0 + nl] = v;
    }
}

// ---------------------------------------------------------------------------
// Split-bf16 MFMA flash attention.
// Round-11 structure: cooperative LDS staging (round 10) + T2 XOR swizzle
// (unpadded power-of-2 rows, 16B-slot ^= row&7 on BOTH write & read) +
// T14 async staging (global loads for tile t+1 issued before compute of
// tile t, held in registers; ds_write after the next barrier).
// grid (N/64, B), block 256 = 4 waves. LDS: K 64KB + V 64KB + P 18KB =146KB.
// ---------------------------------------------------------------------------
__global__ __launch_bounds__(256, 1) void attn_kernel(
    const __bf16* __restrict__ Qh, const __bf16* __restrict__ Ql,
    const __bf16* __restrict__ Kh, const __bf16* __restrict__ Kl,
    const __bf16* __restrict__ Vth, const __bf16* __restrict__ Vtl,
    float* __restrict__ O)
{
    const int b  = blockIdx.y;
    const int n0 = blockIdx.x * 64;
    const size_t base = (size_t)b * N_ * C_;

    const int tid  = threadIdx.x;
    const int w    = tid >> 6;
    const int lane = tid & 63;
    const int l15  = lane & 15;
    const int lg   = lane >> 4;
    const int hsw  = l15 & 7;           // per-lane swizzle constant

    __shared__ __align__(16) __bf16 Ksh[2][64][256];   // 64 KiB (hi,lo)
    __shared__ __align__(16) __bf16 Vsh[2][256][64];   // 64 KiB (hi,lo)
    __shared__ __align__(16) __bf16 Pl[4][2][16][72];  // 18 KiB

    // ---- Q fragments: row = l15 (q-row n0+w*16+l15), k = kk*32+lg*8 ----
    const __bf16* qh_p = Qh + base + (size_t)(n0 + w * 16 + l15) * C_ + lg * 8;
    const __bf16* ql_p = Ql + base + (size_t)(n0 + w * 16 + l15) * C_ + lg * 8;
    bf16x8 qfh[8], qfl[8];
    #pragma unroll
    for (int k = 0; k < 8; ++k) {
        qfh[k] = *(const bf16x8*)(qh_p + k * 32);
        qfl[k] = *(const bf16x8*)(ql_p + k * 32);
    }

    f32x4 oc[16];
    #pragma unroll
    for (int c = 0; c < 16; ++c) oc[c] = (f32x4){0.f, 0.f, 0.f, 0.f};
    float m_run[4] = {-1e30f, -1e30f, -1e30f, -1e30f};
    float l_run[4] = {0.f, 0.f, 0.f, 0.f};

    // staging registers (tile in flight): 32 x 16B
    bf16x8 krH[8], krL[8], vrH[8], vrL[8];

    // ---- prologue: issue loads for tile 0 ----
    #pragma unroll
    for (int i = 0; i < 8; ++i) {
        int f = i * 256 + tid;
        int r = f >> 5, s = f & 31;
        krH[i] = *(const bf16x8*)(Kh + base + (size_t)(0 + r) * C_ + s * 8);
        krL[i] = *(const bf16x8*)(Kl + base + (size_t)(0 + r) * C_ + s * 8);
        int c = f >> 3, sv = f & 7;
        vrH[i] = *(const bf16x8*)(Vth + base + (size_t)c * N_ + 0 + sv * 8);
        vrL[i] = *(const bf16x8*)(Vtl + base + (size_t)c * N_ + 0 + sv * 8);
    }

    for (int mt = 0; mt < N_; mt += 64) {
        __syncthreads();   // all waves done reading previous tile's LDS

        // ---- write in-flight tile to LDS (swizzled dest) ----
        #pragma unroll
        for (int i = 0; i < 8; ++i) {
            int f = i * 256 + tid;
            int r = f >> 5, s = f & 31;
            *(bf16x8*)&Ksh[0][r][(s ^ (r & 7)) * 8] = krH[i];
            *(bf16x8*)&Ksh[1][r][(s ^ (r & 7)) * 8] = krL[i];
            int c = f >> 3, sv = f & 7;
            *(bf16x8*)&Vsh[0][c][(sv ^ (c & 7)) * 8] = vrH[i];
            *(bf16x8*)&Vsh[1][c][(sv ^ (c & 7)) * 8] = vrL[i];
        }
        __syncthreads();   // staged tile visible to all waves

        // ---- issue next tile's loads; latency hides under compute below ----
        if (mt + 64 < N_) {
            const int nmt = mt + 64;
            #pragma unroll
            for (int i = 0; i < 8; ++i) {
                int f = i * 256 + tid;
                int r = f >> 5, s = f & 31;
                krH[i] = *(const bf16x8*)(Kh + base + (size_t)(nmt + r) * C_ + s * 8);
                krL[i] = *(const bf16x8*)(Kl + base + (size_t)(nmt + r) * C_ + s * 8);
                int c = f >> 3, sv = f & 7;
                vrH[i] = *(const bf16x8*)(Vth + base + (size_t)c * N_ + nmt + sv * 8);
                vrL[i] = *(const bf16x8*)(Vtl + base + (size_t)c * N_ + nmt + sv * 8);
            }
        }

        // ---------------- S = Q K^T (B-frags from swizzled LDS) ----------------
        f32x4 sacc[4];
        #pragma unroll
        for (int js = 0; js < 4; ++js) sacc[js] = (f32x4){0.f, 0.f, 0.f, 0.f};

        #pragma unroll
        for (int kk = 0; kk < 8; ++kk) {
            #pragma unroll
            for (int js = 0; js < 4; ++js) {
                bf16x8 kfh = *(const bf16x8*)&Ksh[0][js * 16 + l15][((kk * 4 + lg) ^ hsw) * 8];
                bf16x8 kfl = *(const bf16x8*)&Ksh[1][js * 16 + l15][((kk * 4 + lg) ^ hsw) * 8];
                sacc[js] = __builtin_amdgcn_mfma_f32_16x16x32_bf16(qfh[kk], kfh, sacc[js], 0, 0, 0);
                sacc[js] = __builtin_amdgcn_mfma_f32_16x16x32_bf16(qfh[kk], kfl, sacc[js], 0, 0, 0);
                sacc[js] = __builtin_amdgcn_mfma_f32_16x16x32_bf16(qfl[kk], kfh, sacc[js], 0, 0, 0);
            }
        }

        // ---------------- online softmax (rows lg*4+r) ----------------
        float scale_[4];
        #pragma unroll
        for (int r = 0; r < 4; ++r) {
            float mx = fmaxf(fmaxf(sacc[0][r], sacc[1][r]), fmaxf(sacc[2][r], sacc[3][r]));
            #pragma unroll
            for (int d = 1; d < 16; d <<= 1)
                mx = fmaxf(mx, __shfl_xor(mx, d, 64));
            float mnew = fmaxf(m_run[r], mx);
            scale_[r] = __expf(m_run[r] - mnew);
            float ss = 0.f;
            #pragma unroll
            for (int js = 0; js < 4; ++js) {
                float pv = __expf(sacc[js][r] - mnew);
                sacc[js][r] = pv;
                ss += pv;
            }
            #pragma unroll
            for (int d = 1; d < 16; d <<= 1)
                ss += __shfl_xor(ss, d, 64);
            l_run[r] = l_run[r] * scale_[r] + ss;
            m_run[r] = mnew;
        }

        // ---- P -> wave-private LDS (hi/lo); within-wave RAW, no barrier ----
        #pragma unroll
        for (int js = 0; js < 4; ++js)
            #pragma unroll
            for (int r = 0; r < 4; ++r) {
                float pv = sacc[js][r];
                __bf16 hh = (__bf16)pv;
                __bf16 ll = (__bf16)(pv - (float)hh);
                Pl[w][0][lg * 4 + r][js * 16 + l15] = hh;
                Pl[w][1][lg * 4 + r][js * 16 + l15] = ll;
            }

        #pragma unroll
        for (int c = 0; c < 16; ++c)
            #pragma unroll
            for (int r = 0; r < 4; ++r)
                oc[c][r] *= scale_[r];

        bf16x8 pah0 = *(const bf16x8*)&Pl[w][0][l15][lg * 8];
        bf16x8 pah1 = *(const bf16x8*)&Pl[w][0][l15][32 + lg * 8];
        bf16x8 pal0 = *(const bf16x8*)&Pl[w][1][l15][lg * 8];
        bf16x8 pal1 = *(const bf16x8*)&Pl[w][1][l15][32 + lg * 8];

        // ---------------- O += P V (B-frags from swizzled LDS) ----------------
        #pragma unroll
        for (int cs = 0; cs < 16; ++cs) {
            bf16x8 vh0 = *(const bf16x8*)&Vsh[0][cs * 16 + l15][(lg ^ hsw) * 8];
            bf16x8 vh1 = *(const bf16x8*)&Vsh[0][cs * 16 + l15][((lg + 4) ^ hsw) * 8];
            bf16x8 vl0 = *(const bf16x8*)&Vsh[1][cs * 16 + l15][(lg ^ hsw) * 8];
            bf16x8 vl1 = *(const bf16x8*)&Vsh[1][cs * 16 + l15][((lg + 4) ^ hsw) * 8];
            f32x4 a = oc[cs];
            a = __builtin_amdgcn_mfma_f32_16x16x32_bf16(pah0, vh0, a, 0, 0, 0);
            a = __builtin_amdgcn_mfma_f32_16x16x32_bf16(pah0, vl0, a, 0, 0, 0);
            a = __builtin_amdgcn_mfma_f32_16x16x32_bf16(pal0, vh0, a, 0, 0, 0);
            a = __builtin_amdgcn_mfma_f32_16x16x32_bf16(pah1, vh1, a, 0, 0, 0);
            a = __builtin_amdgcn_mfma_f32_16x16x32_bf16(pah1, vl1, a, 0, 0, 0);
            a = __builtin_amdgcn_mfma_f32_16x16x32_bf16(pal1, vh1, a, 0, 0, 0);
            oc[cs] = a;
        }
    }

    // ---------------- epilogue: normalize + store ----------------
    float inv[4];
    #pragma unroll
    for (int r = 0; r < 4; ++r) inv[r] = 1.0f / l_run[r];
    #pragma unroll
    for (int cs = 0; cs < 16; ++cs)
        #pragma unroll
        for (int r = 0; r < 4; ++r)
            O[base + (size_t)(n0 + w * 16 + lg * 4 + r) * C_ + cs * 16 + l15] =
                oc[cs][r] * inv[r];
}

// ---------------------------------------------------------------------------
extern "C" void kernel_launch(void* const* d_in, const int* in_sizes, int n_in,
                              void* d_out, int out_size, void* d_ws, size_t ws_size,
                              hipStream_t stream)
{
    const float* tgt = (const float*)d_in[0];
    const float* src = (const float*)d_in[1];
    const float* qw  = (const float*)d_in[2];
    const float* qb  = (const float*)d_in[3];
    const float* kw  = (const float*)d_in[4];
    const float* kb  = (const float*)d_in[5];
    const float* vw  = (const float*)d_in[6];
    const float* vb  = (const float*)d_in[7];
    float* out = (float*)d_out;

    // ws: 6 bf16 buffers (Qh Ql Kh Kl Vth Vtl) = 50.3 MB (proven fit)
    const size_t SZ = (size_t)B_ * N_ * C_;
    __bf16* w0 = (__bf16*)d_ws;
    __bf16* w1 = w0 + SZ;
    __bf16* w2 = w1 + SZ;
    __bf16* w3 = w2 + SZ;
    __bf16* w4 = w3 + SZ;
    __bf16* w5 = w4 + SZ;

    dim3 pgrid(P_ / 64, C_ / 64, B_);
    // 1) V projection -> Vnc (into future-Q region)
    proj_kernel<<<pgrid, 256, 0, stream>>>(src, vw, vb, w0, w1);
    // 2) transpose Vnc -> Vt
    dim3 tgrid(N_ / 64, C_ / 64, B_ * 2);
    transpose_kernel<<<tgrid, 256, 0, stream>>>(
        (const ushort*)w0, (const ushort*)w1, (ushort*)w4, (ushort*)w5);
    // 3) Q projection (overwrites dead Vnc)
    proj_kernel<<<pgrid, 256, 0, stream>>>(tgt, qw, qb, w0, w1);
    // 4) K projection
    proj_kernel<<<pgrid, 256, 0, stream>>>(src, kw, kb, w2, w3);
    // 5) attention (async-staged, swizzled LDS)
    dim3 agrid(N_ / 64, B_);
    attn_kernel<<<agrid, 256, 0, stream>>>(w0, w1, w2, w3, w4, w5, out);
}